// Round 15
// baseline (249.011 us; speedup 1.0000x reference)
//
#include <hip/hip_runtime.h>
#include <hip/hip_cooperative_groups.h>

namespace cg = cooperative_groups;

#define H_IMG 128
#define W_IMG 48
#define CIN   64
#define DM    32
#define NPIX  6144
#define WPAD  50
#define HPAD  130

// 0.5 (dh^-0.5) * log2(e): folded into wq/bq at convert time
#define Q_SCALE 0.7213475204444817f

typedef _Float16 half4 __attribute__((ext_vector_type(4)));
typedef __fp16   fp16x2 __attribute__((ext_vector_type(2)));
typedef float    f32x4 __attribute__((ext_vector_type(4)));

__device__ __forceinline__ float fexp2(float x) { return __builtin_amdgcn_exp2f(x); }

__device__ __forceinline__ half4 exp_pack(f32x4 s) {
    fp16x2 lo = __builtin_amdgcn_cvt_pkrtz(fexp2(s[0]), fexp2(s[1]));
    fp16x2 hi = __builtin_amdgcn_cvt_pkrtz(fexp2(s[2]), fexp2(s[3]));
    half4 p;
    p[0] = (_Float16)lo[0]; p[1] = (_Float16)lo[1];
    p[2] = (_Float16)hi[0]; p[3] = (_Float16)hi[1];
    return p;
}

// ---------------------------------------------------------------------------
// One fused kernel, 4 phases.  phase == -1: run all phases with grid.sync()
// between them (cooperative launch).  phase == k: run only phase k (fallback
// path, 4 ordinary launches).  All phases are grid-stride, barrier-uniform
// per block (work counts are multiples of the per-block team counts).
// ---------------------------------------------------------------------------
__global__ __launch_bounds__(512, 8) void fused_kernel(
    const float* __restrict__ x,
    const float* __restrict__ wq, const float* __restrict__ bq,
    const float* __restrict__ wk, const float* __restrict__ bk,
    const float* __restrict__ wv, const float* __restrict__ bv,
    const float* __restrict__ wo,
    _Float16* __restrict__ xpad, _Float16* __restrict__ vT,
    _Float16* __restrict__ attpad,
    _Float16* __restrict__ whT, _Float16* __restrict__ whoT,
    half4* __restrict__ qhi, half4* __restrict__ qlo,
    half4* __restrict__ khi, half4* __restrict__ klo,
    float* __restrict__ out, int phase)
{
    __shared__ __align__(16) char ldsbuf[16384];
    const int tid  = threadIdx.x;
    const int bid  = blockIdx.x;
    const int nb   = gridDim.x;
    const int wav  = __builtin_amdgcn_readfirstlane(tid >> 6);   // 0..7
    const int lane = tid & 63;
    const int r    = lane & 15;
    const int g16  = lane >> 4;

    // ---------------- P0: setup (one load + one store per item) -----------
    if (phase == -1 || phase == 0) {
        for (int u = bid * 512 + tid; u < 242016; u += nb * 512) {
            if (u < 104000) {                     // xpad f32->f16, zero border
                const int pp = u >> 4, j = u & 15;
                const int py = pp / WPAD, px = pp % WPAD;
                half4* dst = reinterpret_cast<half4*>(xpad + (size_t)pp * CIN) + j;
                if (py >= 1 && py <= H_IMG && px >= 1 && px <= W_IMG) {
                    const float4 v = *reinterpret_cast<const float4*>(
                        x + ((size_t)(py - 1) * W_IMG + (px - 1)) * CIN + j * 4);
                    half4 hv = { (_Float16)v.x, (_Float16)v.y,
                                 (_Float16)v.z, (_Float16)v.w };
                    *dst = hv;
                } else {
                    const half4 z = {};
                    *dst = z;
                }
            } else if (u < 156000) {              // attpad zero
                const half4 z = {};
                reinterpret_cast<half4*>(attpad)[u - 104000] = z;
            } else if (u < 168288) {              // vT ones planes (h*5+4)
                const int t = u - 156000;
                const int h = t / 1536, i = t % 1536;
                half4 ones = { (_Float16)1.0f, (_Float16)1.0f,
                               (_Float16)1.0f, (_Float16)1.0f };
                reinterpret_cast<half4*>(vT + (size_t)(h * 5 + 4) * NPIX)[i] = ones;
            } else if (u < 223584) {              // whT (Q_SCALE folded, m=0)
                const int t = u - 168288;
                const int m = t / 18432, rem = t % 18432;
                const int c = rem / 576, kidx = rem % 576;
                const int tap = kidx / 64, ci = kidx % 64;
                const float* w = (m == 0) ? wq : (m == 1) ? wk : wv;
                const float s = (m == 0) ? Q_SCALE : 1.0f;
                whT[t] = (_Float16)(w[(size_t)tap * CIN * DM + (size_t)ci * DM + c] * s);
            } else {                              // whoT
                const int t = u - 223584;
                const int c = t / 288, kidx = t % 288;
                const int tap = kidx / 32, ci = kidx % 32;
                whoT[t] = (_Float16)wo[(size_t)tap * DM * 64 + (size_t)ci * 64 + c];
            }
        }
    }
    if (phase == -1) cg::this_grid().sync();

    // ---------------- P1: QKV conv MFMA GEMM (2-wave K-split teams) -------
    // 2304 tiles = (m,nt,pt); team = 2 waves (hf = K-half, 18 mfma each).
    if (phase == -1 || phase == 1) {
        f32x4* partial = reinterpret_cast<f32x4*>(ldsbuf);            // [4][64]
        _Float16* ltb  = reinterpret_cast<_Float16*>(ldsbuf + 4096);  // [4][2][16][20]
        const int tm = wav >> 1, hf = wav & 1;
        for (int tile = bid * 4 + tm; tile < 2304; tile += nb * 4) {
            const int pt  = tile % 384;
            const int ntm = tile / 384;
            const int nt  = ntm % 2, m = ntm / 2;
            const int p   = pt * 16 + r;
            const int y   = p / W_IMG, x0 = p % W_IMG;
            const _Float16* xb = xpad + ((size_t)y * WPAD + x0) * CIN + 4 * g16;
            const int ch = nt * 16 + r;
            const _Float16* wb = whT + ((size_t)(m * 32 + ch)) * 576 + 4 * g16;

            f32x4 acc[4] = {{0,0,0,0},{0,0,0,0},{0,0,0,0},{0,0,0,0}};
            #pragma unroll
            for (int ii = 0; ii < 18; ++ii) {
                const int i   = hf * 18 + ii;       // hf is scalar (SALU addr)
                const int tap = i >> 2, cb = i & 3;
                const int dy  = tap / 3, dx = tap % 3;
                const half4 xa = *reinterpret_cast<const half4*>(
                    xb + (dy * WPAD + dx) * CIN + cb * 16);
                const half4 wf = *reinterpret_cast<const half4*>(
                    wb + tap * 64 + cb * 16);
                acc[ii & 3] = __builtin_amdgcn_mfma_f32_16x16x16f16(xa, wf, acc[ii & 3], 0, 0, 0);
            }
            f32x4 o = (acc[0] + acc[1]) + (acc[2] + acc[3]);

            if (hf == 1) partial[tm * 64 + lane] = o;
            __syncthreads();
            if (hf == 0) {
                o += partial[tm * 64 + lane];
                const float* b = (m == 0) ? bq : (m == 1) ? bk : bv;
                const float bias = b[ch] * ((m == 0) ? Q_SCALE : 1.0f);
                #pragma unroll
                for (int j = 0; j < 4; ++j) o[j] += bias;

                if (m == 2) {
                    const int plane = (ch >> 2) * 5 + (ch & 3);
                    const int pix0 = pt * 16 + 4 * g16;
                    half4 hv = { (_Float16)o[0], (_Float16)o[1],
                                 (_Float16)o[2], (_Float16)o[3] };
                    *reinterpret_cast<half4*>(vT + (size_t)plane * NPIX + pix0) = hv;
                } else {
                    _Float16* lt = ltb + tm * 640;   // [2][16][20] per team
                    #pragma unroll
                    for (int j = 0; j < 4; ++j) {
                        const float val = o[j];
                        const _Float16 hi = (_Float16)val;
                        const _Float16 lo = (_Float16)(val - (float)hi);
                        lt[(4 * g16 + j) * 20 + r]       = hi;
                        lt[320 + (4 * g16 + j) * 20 + r] = lo;
                    }
                    const int p4 = lane & 15;            // same-wave readback
                    const int hh = lane >> 4;
                    const half4 hv = *reinterpret_cast<const half4*>(lt + p4 * 20 + hh * 4);
                    const half4 lv = *reinterpret_cast<const half4*>(lt + 320 + p4 * 20 + hh * 4);
                    const int h = nt * 4 + hh;
                    const size_t idx = (size_t)h * NPIX + pt * 16 + p4;
                    ((half4*)((m == 0) ? qhi : khi))[idx] = hv;
                    ((half4*)((m == 0) ? qlo : klo))[idx] = lv;
                }
            }
            __syncthreads();
        }
    }
    if (phase == -1) cg::this_grid().sync();

    // ---------------- P2: fused attention (R12-validated 8-wave unit) -----
    if (phase == -1 || phase == 2) {
        f32x4* red = reinterpret_cast<f32x4*>(ldsbuf);   // [8][2][64]
        for (int ub = bid; ub < 768; ub += nb) {
            const int hg = ub / 48;
            const int qq = ub % 48;
            const int h = hg >> 1, g = hg & 1;
            const int seg = wav >> 1;
            const int u   = wav & 1;
            const int qt0 = qq * 4 + u * 2;
            const int c   = r;
            const int c0  = g * 16;

            half4 qfA = {}, qfB = {};
            {
                const half4* qsrc = (g16 == 1) ? qlo : qhi;
                const int qa  = qt0 * 16 + c;
                const int qay = qa / 24;
                const int qb  = qa + 16;
                const int qby = qb / 24;
                if (g16 < 3) {
                    qfA = qsrc[h * NPIX + qay * W_IMG + g * 24 + (qa - qay * 24)];
                    qfB = qsrc[h * NPIX + qby * W_IMG + g * 24 + (qb - qby * 24)];
                }
            }

            const half4* kb = ((g16 == 2) ? klo : khi) + h * NPIX + c;
            const int vplane = (c < 4) ? c : 4;
            const _Float16* vb = vT + (h * 5 + vplane) * NPIX + 4 * g16;

            const f32x4 zc = {0.f, 0.f, 0.f, 0.f};
            f32x4 oA0 = zc, oA1 = zc, oB0 = zc, oB1 = zc;

            const int r0 = seg * 32;
            #pragma unroll 4
            for (int rr = 0; rr < 32; ++rr) {
                const int koff = (r0 + rr) * W_IMG + c0;

                const half4 k0 = kb[koff];
                const half4 k1 = kb[koff + 16];
                const half4 v0 = *reinterpret_cast<const half4*>(vb + koff);
                const half4 v1 = *reinterpret_cast<const half4*>(vb + koff + 16);

                const f32x4 sA0 = __builtin_amdgcn_mfma_f32_16x16x16f16(k0, qfA, zc, 0, 0, 0);
                const f32x4 sA1 = __builtin_amdgcn_mfma_f32_16x16x16f16(k1, qfA, zc, 0, 0, 0);
                const f32x4 sB0 = __builtin_amdgcn_mfma_f32_16x16x16f16(k0, qfB, zc, 0, 0, 0);
                const f32x4 sB1 = __builtin_amdgcn_mfma_f32_16x16x16f16(k1, qfB, zc, 0, 0, 0);

                const half4 pA0 = exp_pack(sA0);
                const half4 pA1 = exp_pack(sA1);
                const half4 pB0 = exp_pack(sB0);
                const half4 pB1 = exp_pack(sB1);

                oA0 = __builtin_amdgcn_mfma_f32_16x16x16f16(pA0, v0, oA0, 0, 0, 0);
                oA1 = __builtin_amdgcn_mfma_f32_16x16x16f16(pA1, v1, oA1, 0, 0, 0);
                oB0 = __builtin_amdgcn_mfma_f32_16x16x16f16(pB0, v0, oB0, 0, 0, 0);
                oB1 = __builtin_amdgcn_mfma_f32_16x16x16f16(pB1, v1, oB1, 0, 0, 0);
            }

            red[(wav * 2 + 0) * 64 + lane] = oA0 + oA1;
            red[(wav * 2 + 1) * 64 + lane] = oB0 + oB1;
            __syncthreads();

            if (wav < 4) {
                const int t = seg;                 // tile within pair (0/1)
                f32x4 o = red[((0 + u) * 2 + t) * 64 + lane];
                o += red[((2 + u) * 2 + t) * 64 + lane];
                o += red[((4 + u) * 2 + t) * 64 + lane];
                o += red[((6 + u) * 2 + t) * 64 + lane];

                const int baddr = (g16 * 16 + 4) << 2;  // ssum column lane
                f32x4 on;
                #pragma unroll
                for (int j = 0; j < 4; ++j) {
                    const float ss = __int_as_float(
                        __builtin_amdgcn_ds_bpermute(baddr, __float_as_int(o[j])));
                    on[j] = o[j] * __builtin_amdgcn_rcpf(ss);
                }

                if (c < 4) {
                    const int qt = qt0 + t;
                    #pragma unroll
                    for (int j = 0; j < 4; ++j) {
                        const int q  = qt * 16 + 4 * g16 + j;
                        const int qy = q / 24;
                        const int qx = g * 24 + (q - qy * 24);
                        attpad[((size_t)(qy + 1) * WPAD + qx + 1) * DM + h * 4 + c] =
                            (_Float16)on[j];
                    }
                }
            }
            __syncthreads();
        }
    }
    if (phase == -1) cg::this_grid().sync();

    // ---------------- P3: out conv MFMA GEMM (2-wave K-split teams) -------
    if (phase == -1 || phase == 3) {
        f32x4* po = reinterpret_cast<f32x4*>(ldsbuf);    // [4][64]
        const int tm = wav >> 1, hf = wav & 1;
        for (int tile = bid * 4 + tm; tile < 1536; tile += nb * 4) {
            const int pt = tile % 384;
            const int nt = tile / 384;                   // 0..3
            const int p  = pt * 16 + r;
            const int y  = p / W_IMG, x0 = p % W_IMG;
            const _Float16* ab = attpad + ((size_t)y * WPAD + x0) * DM + 4 * g16;
            const int ch = nt * 16 + r;
            const _Float16* wb = whoT + (size_t)ch * 288 + 4 * g16;

            f32x4 a0 = {0,0,0,0}, a1 = {0,0,0,0};
            #pragma unroll
            for (int ii = 0; ii < 9; ++ii) {
                const int i   = hf * 9 + ii;
                const int tap = i >> 1, cb = i & 1;
                const int dy  = tap / 3, dx = tap % 3;
                const half4 xa = *reinterpret_cast<const half4*>(
                    ab + (dy * WPAD + dx) * DM + cb * 16);
                const half4 wf = *reinterpret_cast<const half4*>(
                    wb + tap * 32 + cb * 16);
                if (ii & 1) a1 = __builtin_amdgcn_mfma_f32_16x16x16f16(xa, wf, a1, 0, 0, 0);
                else        a0 = __builtin_amdgcn_mfma_f32_16x16x16f16(xa, wf, a0, 0, 0, 0);
            }
            f32x4 o = a0 + a1;

            if (hf == 1) po[tm * 64 + lane] = o;
            __syncthreads();
            if (hf == 0) {
                o += po[tm * 64 + lane];
                const int pix0 = pt * 16 + 4 * g16;
                #pragma unroll
                for (int j = 0; j < 4; ++j)
                    out[(size_t)(pix0 + j) * 64 + nt * 16 + r] = o[j];
            }
            __syncthreads();
        }
    }
}

// ---------------------------------------------------------------------------
extern "C" void kernel_launch(void* const* d_in, const int* in_sizes, int n_in,
                              void* d_out, int out_size, void* d_ws, size_t ws_size,
                              hipStream_t stream)
{
    const float* x  = (const float*)d_in[0];
    const float* wq = (const float*)d_in[1];
    const float* bq = (const float*)d_in[2];
    const float* wk = (const float*)d_in[3];
    const float* bk = (const float*)d_in[4];
    const float* wv = (const float*)d_in[5];
    const float* bv = (const float*)d_in[6];
    const float* wo = (const float*)d_in[7];
    float* out = (float*)d_out;

    // workspace layout (bytes) — identical to R14
    char* base = (char*)d_ws;
    half4*    qhi    = (half4*)(base + 0);          //  393216
    half4*    qlo    = (half4*)(base + 393216);
    half4*    khi    = (half4*)(base + 786432);
    half4*    klo    = (half4*)(base + 1179648);
    _Float16* vT     = (_Float16*)(base + 1572864); //  491520 (8h x 5 planes)
    _Float16* xpad   = (_Float16*)(base + 2064384); //  832000 -> 2896384
    _Float16* attpad = (_Float16*)(base + 2896384); //  416000 -> 3312384
    _Float16* whT    = (_Float16*)(base + 3312384); //  110592 -> 3422976
    _Float16* whoT   = (_Float16*)(base + 3422976); //   36864 -> 3459840

    // capture-safe host queries (no stream ops)
    int dev = 0;
    hipGetDevice(&dev);
    int coop = 0;
    hipDeviceGetAttribute(&coop, hipDeviceAttributeCooperativeLaunch, dev);
    int maxb = 0;
    hipOccupancyMaxActiveBlocksPerMultiprocessor(&maxb, fused_kernel, 512, 0);

    bool done = false;
    int phase = -1;
    if (coop && maxb > 0) {
        int nblk = maxb * 256;
        if (nblk > 1024) nblk = 1024;
        void* args[] = {
            (void*)&x, (void*)&wq, (void*)&bq, (void*)&wk, (void*)&bk,
            (void*)&wv, (void*)&bv, (void*)&wo,
            (void*)&xpad, (void*)&vT, (void*)&attpad, (void*)&whT, (void*)&whoT,
            (void*)&qhi, (void*)&qlo, (void*)&khi, (void*)&klo,
            (void*)&out, (void*)&phase
        };
        if (hipLaunchCooperativeKernel((const void*)fused_kernel, dim3(nblk),
                                       dim3(512), args, 0, stream) == hipSuccess)
            done = true;
    }
    if (!done) {
        for (int ph = 0; ph < 4; ++ph)
            hipLaunchKernelGGL(fused_kernel, dim3(1024), dim3(512), 0, stream,
                               x, wq, bq, wk, bk, wv, bv, wo,
                               xpad, vT, attpad, whT, whoT,
                               qhi, qlo, khi, klo, out, ph);
    }
}

// Round 16
// 99.958 us; speedup vs baseline: 2.4912x; 2.4912x over previous
//
#include <hip/hip_runtime.h>

#define H_IMG 128
#define W_IMG 48
#define CIN   64
#define DM    32
#define NH    8
#define NPIX  6144
#define WPAD  50
#define HPAD  130

// 0.5 (dh^-0.5) * log2(e): folded into wq/bq at convert time
#define Q_SCALE 0.7213475204444817f

typedef _Float16 half4 __attribute__((ext_vector_type(4)));
typedef __fp16   fp16x2 __attribute__((ext_vector_type(2)));
typedef float    f32x4 __attribute__((ext_vector_type(4)));

__device__ __forceinline__ float fexp2(float x) { return __builtin_amdgcn_exp2f(x); }

__device__ __forceinline__ half4 exp_pack(f32x4 s) {
    fp16x2 lo = __builtin_amdgcn_cvt_pkrtz(fexp2(s[0]), fexp2(s[1]));
    fp16x2 hi = __builtin_amdgcn_cvt_pkrtz(fexp2(s[2]), fexp2(s[3]));
    half4 p;
    p[0] = (_Float16)lo[0]; p[1] = (_Float16)lo[1];
    p[2] = (_Float16)hi[0]; p[3] = (_Float16)hi[1];
    return p;
}

// ---------------------------------------------------------------------------
// K0: setup — xpad f16 (zero border), vT ones planes, attpad zero,
// whT[m][32][576] (Q_SCALE folded into m=0), whoT[64][288] (one elem/thread).
// blocks: [0,26) xpad | 26 vT-ones | [27,53) attpad | [53,269) whT | [269,341) whoT
// ---------------------------------------------------------------------------
__global__ __launch_bounds__(256) void setup_kernel(
    const float* __restrict__ x,
    const float* __restrict__ wq, const float* __restrict__ wk,
    const float* __restrict__ wv, const float* __restrict__ wo,
    _Float16* __restrict__ xpad, _Float16* __restrict__ vT,
    _Float16* __restrict__ attpad,
    _Float16* __restrict__ whT, _Float16* __restrict__ whoT)
{
    const int bid = blockIdx.x;
    const int tid = threadIdx.x;

    if (bid < 26) {                       // xpad: one padded pixel per thread
        const int pp = bid * 256 + tid;
        if (pp < HPAD * WPAD) {
            const int py = pp / WPAD, px = pp % WPAD;
            _Float16* dst = xpad + (size_t)pp * CIN;
            if (py >= 1 && py <= H_IMG && px >= 1 && px <= W_IMG) {
                const float* src = x + ((size_t)(py - 1) * W_IMG + (px - 1)) * CIN;
                #pragma unroll
                for (int c = 0; c < CIN; c += 4) {
                    const float4 v = *reinterpret_cast<const float4*>(src + c);
                    half4 hv = { (_Float16)v.x, (_Float16)v.y, (_Float16)v.z, (_Float16)v.w };
                    *reinterpret_cast<half4*>(dst + c) = hv;
                }
            } else {
                const half4 z = {};
                #pragma unroll
                for (int c = 0; c < CIN; c += 4)
                    *reinterpret_cast<half4*>(dst + c) = z;
            }
        }
    } else if (bid == 26) {               // vT ones planes (h*5+4)
        const int h = tid >> 5, chunk = tid & 31;
        _Float16* dst = vT + ((size_t)(h * 5 + 4)) * NPIX + chunk * (NPIX / 32);
        half4 ones = { (_Float16)1.0f, (_Float16)1.0f, (_Float16)1.0f, (_Float16)1.0f };
        #pragma unroll
        for (int i = 0; i < NPIX / 32; i += 4)
            *reinterpret_cast<half4*>(dst + i) = ones;
    } else if (bid < 53) {                // attpad zero
        const int pp = (bid - 27) * 256 + tid;
        if (pp < HPAD * WPAD) {
            _Float16* dst = attpad + (size_t)pp * DM;
            const half4 z = {};
            #pragma unroll
            for (int c = 0; c < DM; c += 4)
                *reinterpret_cast<half4*>(dst + c) = z;
        }
    } else if (bid < 269) {               // whT: one element per thread
        const int u = (bid - 53) * 256 + tid;
        if (u < 3 * 32 * 576) {
            const int m    = u / 18432;
            const int rem  = u % 18432;
            const int c    = rem / 576;
            const int kidx = rem % 576;
            const int tap  = kidx / 64;
            const int ci   = kidx % 64;
            const float* w = (m == 0) ? wq : (m == 1) ? wk : wv;
            const float s  = (m == 0) ? Q_SCALE : 1.0f;
            whT[u] = (_Float16)(w[(size_t)tap * CIN * DM + (size_t)ci * DM + c] * s);
        }
    } else {                              // whoT: one element per thread
        const int u = (bid - 269) * 256 + tid;
        if (u < 64 * 288) {
            const int c    = u / 288;
            const int kidx = u % 288;
            const int tap  = kidx / 32;
            const int ci   = kidx % 32;
            whoT[u] = (_Float16)wo[(size_t)tap * DM * 64 + (size_t)ci * 64 + c];
        }
    }
}

// ---------------------------------------------------------------------------
// K1: QKV conv as MFMA GEMM, dy-split (validated R13).
// ---------------------------------------------------------------------------
__global__ __launch_bounds__(192) void qkv_mfma_kernel(
    const _Float16* __restrict__ xpad,
    const _Float16* __restrict__ whT,
    const float* __restrict__ bq, const float* __restrict__ bk,
    const float* __restrict__ bv,
    half4* __restrict__ qhi, half4* __restrict__ qlo,
    half4* __restrict__ khi, half4* __restrict__ klo,
    _Float16* __restrict__ vT)
{
    __shared__ f32x4 redq[2][64];
    __shared__ _Float16 lt[2][16][20];

    const int pt  = blockIdx.x % 384;
    const int ntm = blockIdx.x / 384;
    const int nt  = ntm % 2;
    const int m   = ntm / 2;
    const int wav = __builtin_amdgcn_readfirstlane(threadIdx.x >> 6);  // = dy
    const int lane = threadIdx.x & 63;
    const int r    = lane & 15;
    const int g16  = lane >> 4;

    const int p  = pt * 16 + r;
    const int y  = p / W_IMG, x0 = p % W_IMG;
    const _Float16* xb = xpad + ((size_t)y * WPAD + x0) * CIN + 4 * g16;

    const int ch = nt * 16 + r;
    const _Float16* wb = whT + ((size_t)(m * 32 + ch)) * 576 + 4 * g16;

    f32x4 acc[4] = {{0.f,0.f,0.f,0.f},{0.f,0.f,0.f,0.f},
                    {0.f,0.f,0.f,0.f},{0.f,0.f,0.f,0.f}};

    const int dy = wav;
    #pragma unroll
    for (int dx = 0; dx < 3; ++dx) {
        const int toff = (dy * WPAD + dx) * CIN;
        const int k0   = (dy * 3 + dx) * 64;
        #pragma unroll
        for (int cb = 0; cb < 4; ++cb) {
            const half4 xa = *reinterpret_cast<const half4*>(xb + toff + cb * 16);
            const half4 wf = *reinterpret_cast<const half4*>(wb + k0 + cb * 16);
            acc[cb] = __builtin_amdgcn_mfma_f32_16x16x16f16(xa, wf, acc[cb], 0, 0, 0);
        }
    }

    f32x4 o = (acc[0] + acc[1]) + (acc[2] + acc[3]);

    if (wav > 0) redq[wav - 1][lane] = o;
    __syncthreads();
    if (wav != 0) return;

    o += redq[0][lane] + redq[1][lane];

    const float* b = (m == 0) ? bq : (m == 1) ? bk : bv;
    const float bias = b[ch] * ((m == 0) ? Q_SCALE : 1.0f);
    #pragma unroll
    for (int j = 0; j < 4; ++j) o[j] += bias;

    if (m == 2) {
        const int plane = (ch >> 2) * 5 + (ch & 3);
        const int pix0 = pt * 16 + 4 * g16;
        half4 hv = { (_Float16)o[0], (_Float16)o[1], (_Float16)o[2], (_Float16)o[3] };
        *reinterpret_cast<half4*>(vT + (size_t)plane * NPIX + pix0) = hv;
    } else {
        #pragma unroll
        for (int j = 0; j < 4; ++j) {
            const float val = o[j];
            const _Float16 hi = (_Float16)val;
            const _Float16 lo = (_Float16)(val - (float)hi);
            lt[0][4 * g16 + j][r] = hi;
            lt[1][4 * g16 + j][r] = lo;
        }
        const int p4 = lane & 15;              // pixel within tile
        const int hh = lane >> 4;              // head within nt-half
        const half4 hv = *reinterpret_cast<const half4*>(&lt[0][p4][hh * 4]);
        const half4 lv = *reinterpret_cast<const half4*>(&lt[1][p4][hh * 4]);
        const int h = nt * 4 + hh;
        const size_t idx = (size_t)h * NPIX + pt * 16 + p4;
        ((half4*)((m == 0) ? qhi : khi))[idx] = hv;
        ((half4*)((m == 0) ? qlo : klo))[idx] = lv;
    }
}

// ---------------------------------------------------------------------------
// K2: fused MFMA local attention + split-K reduce + normalize, SSEG=8
// (validated R13).  IDEMPOTENT: pure function of q/k/v buffers, writes the
// same attpad values on every run — launched twice this round as an A/B
// timing probe for attn's true cost.
// ---------------------------------------------------------------------------
__global__ __launch_bounds__(1024) void attn_mfma_kernel(
    const half4* __restrict__ qhi, const half4* __restrict__ qlo,
    const half4* __restrict__ khi, const half4* __restrict__ klo,
    const _Float16* __restrict__ vT,
    _Float16* __restrict__ attpad)
{
    __shared__ f32x4 red[16][2][64];   // 32 KB

    const int hg  = blockIdx.x / 48;
    const int qq  = blockIdx.x % 48;
    const int h   = hg >> 1, g = hg & 1;
    const int wav = __builtin_amdgcn_readfirstlane(threadIdx.x >> 6);  // 0..15
    const int seg = wav & 7;
    const int u   = wav >> 3;
    const int qt0 = qq * 4 + u * 2;           // tiles qt0, qt0+1
    const int lane = threadIdx.x & 63;
    const int c    = lane & 15;
    const int g16  = lane >> 4;
    const int c0   = g * 16;

    half4 qfA = {}, qfB = {};
    {
        const half4* qsrc = (g16 == 1) ? qlo : qhi;
        const int qa  = qt0 * 16 + c;
        const int qay = qa / 24;
        const int qb  = qa + 16;
        const int qby = qb / 24;
        if (g16 < 3) {
            qfA = qsrc[h * NPIX + qay * W_IMG + g * 24 + (qa - qay * 24)];
            qfB = qsrc[h * NPIX + qby * W_IMG + g * 24 + (qb - qby * 24)];
        }
    }

    const half4* kb = ((g16 == 2) ? klo : khi) + h * NPIX + c;
    const int vplane = (c < 4) ? c : 4;
    const _Float16* vb = vT + (h * 5 + vplane) * NPIX + 4 * g16;

    const f32x4 zc = {0.f, 0.f, 0.f, 0.f};
    f32x4 oA0 = zc, oA1 = zc, oB0 = zc, oB1 = zc;

    const int r0 = seg * 16;
    #pragma unroll 4
    for (int r = 0; r < 16; ++r) {
        const int koff = (r0 + r) * W_IMG + c0;

        const half4 k0 = kb[koff];
        const half4 k1 = kb[koff + 16];
        const half4 v0 = *reinterpret_cast<const half4*>(vb + koff);
        const half4 v1 = *reinterpret_cast<const half4*>(vb + koff + 16);

        const f32x4 sA0 = __builtin_amdgcn_mfma_f32_16x16x16f16(k0, qfA, zc, 0, 0, 0);
        const f32x4 sA1 = __builtin_amdgcn_mfma_f32_16x16x16f16(k1, qfA, zc, 0, 0, 0);
        const f32x4 sB0 = __builtin_amdgcn_mfma_f32_16x16x16f16(k0, qfB, zc, 0, 0, 0);
        const f32x4 sB1 = __builtin_amdgcn_mfma_f32_16x16x16f16(k1, qfB, zc, 0, 0, 0);

        const half4 pA0 = exp_pack(sA0);
        const half4 pA1 = exp_pack(sA1);
        const half4 pB0 = exp_pack(sB0);
        const half4 pB1 = exp_pack(sB1);

        oA0 = __builtin_amdgcn_mfma_f32_16x16x16f16(pA0, v0, oA0, 0, 0, 0);
        oA1 = __builtin_amdgcn_mfma_f32_16x16x16f16(pA1, v1, oA1, 0, 0, 0);
        oB0 = __builtin_amdgcn_mfma_f32_16x16x16f16(pB0, v0, oB0, 0, 0, 0);
        oB1 = __builtin_amdgcn_mfma_f32_16x16x16f16(pB1, v1, oB1, 0, 0, 0);
    }

    red[wav][0][lane] = oA0 + oA1;
    red[wav][1][lane] = oB0 + oB1;
    __syncthreads();

    if (wav < 4) {
        const int u2  = wav >> 1;              // pair group
        const int t01 = wav & 1;               // tile within pair
        f32x4 o = red[u2 * 8 + 0][t01][lane];
        #pragma unroll
        for (int s = 1; s < 8; ++s)
            o += red[u2 * 8 + s][t01][lane];

        const int baddr = (g16 * 16 + 4) << 2; // ssum column lane, in bytes
        f32x4 on;
        #pragma unroll
        for (int r = 0; r < 4; ++r) {
            const float ss = __int_as_float(
                __builtin_amdgcn_ds_bpermute(baddr, __float_as_int(o[r])));
            on[r] = o[r] * __builtin_amdgcn_rcpf(ss);
        }

        if (c < 4) {
            const int qt = qq * 4 + u2 * 2 + t01;
            #pragma unroll
            for (int r = 0; r < 4; ++r) {
                const int q  = qt * 16 + 4 * g16 + r;
                const int qy = q / 24;
                const int qx = g * 24 + (q - qy * 24);
                attpad[((size_t)(qy + 1) * WPAD + qx + 1) * DM + h * 4 + c] =
                    (_Float16)on[r];
            }
        }
    }
}

// ---------------------------------------------------------------------------
// K3: output conv as MFMA GEMM, dy-split (validated R13).
// ---------------------------------------------------------------------------
__global__ __launch_bounds__(192) void out_mfma_kernel(
    const _Float16* __restrict__ attpad,
    const _Float16* __restrict__ whoT,
    float* __restrict__ out)
{
    __shared__ f32x4 redo[2][64];

    const int pt  = blockIdx.x % 384;
    const int nt  = blockIdx.x / 384;        // 0..3
    const int wav = __builtin_amdgcn_readfirstlane(threadIdx.x >> 6);  // = dy
    const int lane = threadIdx.x & 63;
    const int r    = lane & 15;
    const int g16  = lane >> 4;

    const int p  = pt * 16 + r;
    const int y  = p / W_IMG, x0 = p % W_IMG;
    const _Float16* ab = attpad + ((size_t)y * WPAD + x0) * DM + 4 * g16;

    const int ch = nt * 16 + r;
    const _Float16* wb = whoT + (size_t)ch * 288 + 4 * g16;

    f32x4 a0 = {0.f, 0.f, 0.f, 0.f}, a1 = {0.f, 0.f, 0.f, 0.f};

    const int dy = wav;
    #pragma unroll
    for (int dx = 0; dx < 3; ++dx) {
        const int toff = (dy * WPAD + dx) * DM;
        const int k0   = (dy * 3 + dx) * 32;
        const half4 xa0 = *reinterpret_cast<const half4*>(ab + toff);
        const half4 wf0 = *reinterpret_cast<const half4*>(wb + k0);
        a0 = __builtin_amdgcn_mfma_f32_16x16x16f16(xa0, wf0, a0, 0, 0, 0);
        const half4 xa1 = *reinterpret_cast<const half4*>(ab + toff + 16);
        const half4 wf1 = *reinterpret_cast<const half4*>(wb + k0 + 16);
        a1 = __builtin_amdgcn_mfma_f32_16x16x16f16(xa1, wf1, a1, 0, 0, 0);
    }

    f32x4 o = a0 + a1;
    if (wav > 0) redo[wav - 1][lane] = o;
    __syncthreads();
    if (wav != 0) return;

    o += redo[0][lane] + redo[1][lane];

    const int pix0 = pt * 16 + 4 * g16;
    #pragma unroll
    for (int j = 0; j < 4; ++j)
        out[(size_t)(pix0 + j) * 64 + nt * 16 + r] = o[j];
}

// ---------------------------------------------------------------------------
extern "C" void kernel_launch(void* const* d_in, const int* in_sizes, int n_in,
                              void* d_out, int out_size, void* d_ws, size_t ws_size,
                              hipStream_t stream)
{
    const float* x  = (const float*)d_in[0];
    const float* wq = (const float*)d_in[1];
    const float* bq = (const float*)d_in[2];
    const float* wk = (const float*)d_in[3];
    const float* bk = (const float*)d_in[4];
    const float* wv = (const float*)d_in[5];
    const float* bv = (const float*)d_in[6];
    const float* wo = (const float*)d_in[7];
    float* out = (float*)d_out;

    // workspace layout (bytes)
    char* base = (char*)d_ws;
    half4*    qhi    = (half4*)(base + 0);          //  393216
    half4*    qlo    = (half4*)(base + 393216);
    half4*    khi    = (half4*)(base + 786432);
    half4*    klo    = (half4*)(base + 1179648);
    _Float16* vT     = (_Float16*)(base + 1572864); //  491520 (8h x 5 planes)
    _Float16* xpad   = (_Float16*)(base + 2064384); //  832000 -> 2896384
    _Float16* attpad = (_Float16*)(base + 2896384); //  416000 -> 3312384
    _Float16* whT    = (_Float16*)(base + 3312384); //  110592 -> 3422976
    _Float16* whoT   = (_Float16*)(base + 3422976); //   36864 -> 3459840

    hipLaunchKernelGGL(setup_kernel, dim3(341), dim3(256), 0, stream,
                       x, wq, wk, wv, wo, xpad, vT, attpad, whT, whoT);

    hipLaunchKernelGGL(qkv_mfma_kernel, dim3(2304), dim3(192), 0, stream,
                       xpad, whT, bq, bk, bv, qhi, qlo, khi, klo, vT);

    // A/B probe: attention launched twice (idempotent — identical writes).
    // Marginal dur_us vs R13 == attn kernel's true cost.
    hipLaunchKernelGGL(attn_mfma_kernel, dim3(16 * 48), dim3(1024), 0, stream,
                       qhi, qlo, khi, klo, vT, attpad);
    hipLaunchKernelGGL(attn_mfma_kernel, dim3(16 * 48), dim3(1024), 0, stream,
                       qhi, qlo, khi, klo, vT, attpad);

    hipLaunchKernelGGL(out_mfma_kernel, dim3(4 * 384), dim3(192), 0, stream,
                       attpad, whoT, out);
}

// Round 17
// 56.544 us; speedup vs baseline: 4.4038x; 1.7678x over previous
//
#include <hip/hip_runtime.h>

#define H_IMG 128
#define W_IMG 48
#define CIN   64
#define DM    32
#define NH    8
#define NPIX  6144
#define WPAD  50
#define HPAD  130

// 0.5 (dh^-0.5) * log2(e): folded into wq/bq at load time
#define Q_SCALE 0.7213475204444817f

typedef _Float16 half4 __attribute__((ext_vector_type(4)));
typedef __fp16   fp16x2 __attribute__((ext_vector_type(2)));
typedef float    f32x4 __attribute__((ext_vector_type(4)));

__device__ __forceinline__ float fexp2(float x) { return __builtin_amdgcn_exp2f(x); }

__device__ __forceinline__ half4 exp_pack(f32x4 s) {
    fp16x2 lo = __builtin_amdgcn_cvt_pkrtz(fexp2(s[0]), fexp2(s[1]));
    fp16x2 hi = __builtin_amdgcn_cvt_pkrtz(fexp2(s[2]), fexp2(s[3]));
    half4 p;
    p[0] = (_Float16)lo[0]; p[1] = (_Float16)lo[1];
    p[2] = (_Float16)hi[0]; p[3] = (_Float16)hi[1];
    return p;
}

// ---------------------------------------------------------------------------
// K1: QKV conv as MFMA GEMM, dy-split, DIRECT x/w loads (no setup kernel).
// grid = 2304 blocks (pt in [0,384), ntm in [0,6)), 3 waves (wav = dy).
// Each 16-pixel tile lies in ONE image row (48 = 3*16), so yy is
// wave-uniform; only edge-column tiles have lane-divergent masks.
// A lane (g16,r): x[yy][x0c+dx-1][ci], ci = cb*16+4*g16+j (f32->f16 RNE).
// B lane (g16,c=ch): w[tap][ci][ch], stride DM floats, *Q_SCALE for m=0.
// Waves 1,2 deposit partials in LDS; wave 0 sums + bias + validated
// epilogue (LDS transpose -> coalesced q/k hi/lo stores; vT planes).
// Wave 1 of m==2 blocks writes the vT ones plane for its (pt,nt).
// ---------------------------------------------------------------------------
__global__ __launch_bounds__(192) void qkv_mfma_kernel(
    const float* __restrict__ x,
    const float* __restrict__ wq, const float* __restrict__ bq,
    const float* __restrict__ wk, const float* __restrict__ bk,
    const float* __restrict__ wv, const float* __restrict__ bv,
    half4* __restrict__ qhi, half4* __restrict__ qlo,
    half4* __restrict__ khi, half4* __restrict__ klo,
    _Float16* __restrict__ vT)
{
    __shared__ f32x4 redq[2][64];
    __shared__ _Float16 lt[2][16][20];

    const int pt  = blockIdx.x % 384;
    const int ntm = blockIdx.x / 384;
    const int nt  = ntm % 2;
    const int m   = ntm / 2;
    const int wav = __builtin_amdgcn_readfirstlane(threadIdx.x >> 6);  // = dy
    const int lane = threadIdx.x & 63;
    const int r    = lane & 15;
    const int g16  = lane >> 4;

    const int y   = pt / 3;                 // wave-uniform image row
    const int x0c = (pt % 3) * 16 + r;      // pixel column (per lane)
    const int yy  = y + wav - 1;
    const bool vrow = (yy >= 0) && (yy < H_IMG);

    const int ch = nt * 16 + r;
    const float* w = (m == 0) ? wq : (m == 1) ? wk : wv;
    const float  s = (m == 0) ? Q_SCALE : 1.0f;

    f32x4 acc[4] = {{0.f,0.f,0.f,0.f},{0.f,0.f,0.f,0.f},
                    {0.f,0.f,0.f,0.f},{0.f,0.f,0.f,0.f}};

    #pragma unroll
    for (int dx = 0; dx < 3; ++dx) {
        const int xx = x0c + dx - 1;
        const bool v = vrow && (xx >= 0) && (xx < W_IMG);
        const int poff = v ? (yy * W_IMG + xx) : 0;     // clamped when masked
        const float* xsrc = x + (size_t)poff * CIN + 4 * g16;
        const float* wp0  = w + (size_t)(wav * 3 + dx) * CIN * DM + 4 * g16 * DM + ch;
        #pragma unroll
        for (int cb = 0; cb < 4; ++cb) {
            f32x4 xv = {0.f, 0.f, 0.f, 0.f};
            if (v) xv = *reinterpret_cast<const f32x4*>(xsrc + cb * 16);
            half4 xa = { (_Float16)xv[0], (_Float16)xv[1],
                         (_Float16)xv[2], (_Float16)xv[3] };
            const float* wp = wp0 + cb * 16 * DM;
            half4 wf = { (_Float16)(wp[0 * DM] * s), (_Float16)(wp[1 * DM] * s),
                         (_Float16)(wp[2 * DM] * s), (_Float16)(wp[3 * DM] * s) };
            acc[cb] = __builtin_amdgcn_mfma_f32_16x16x16f16(xa, wf, acc[cb], 0, 0, 0);
        }
    }

    f32x4 o = (acc[0] + acc[1]) + (acc[2] + acc[3]);

    if (wav > 0) redq[wav - 1][lane] = o;
    __syncthreads();
    if (wav != 0) {
        if (wav == 1 && m == 2) {           // ones plane for (pt, nt)
            const int pix = pt * 16 + (lane & 15);
            const int h   = nt * 4 + (lane >> 4);
            vT[(size_t)(h * 5 + 4) * NPIX + pix] = (_Float16)1.0f;
        }
        return;
    }

    o += redq[0][lane] + redq[1][lane];

    const float* b = (m == 0) ? bq : (m == 1) ? bk : bv;
    const float bias = b[ch] * s;
    #pragma unroll
    for (int j = 0; j < 4; ++j) o[j] += bias;

    if (m == 2) {
        const int plane = (ch >> 2) * 5 + (ch & 3);
        const int pix0 = pt * 16 + 4 * g16;
        half4 hv = { (_Float16)o[0], (_Float16)o[1], (_Float16)o[2], (_Float16)o[3] };
        *reinterpret_cast<half4*>(vT + (size_t)plane * NPIX + pix0) = hv;
    } else {
        #pragma unroll
        for (int j = 0; j < 4; ++j) {
            const float val = o[j];
            const _Float16 hi = (_Float16)val;
            const _Float16 lo = (_Float16)(val - (float)hi);
            lt[0][4 * g16 + j][r] = hi;
            lt[1][4 * g16 + j][r] = lo;
        }
        const int p4 = lane & 15;              // pixel within tile
        const int hh = lane >> 4;              // head within nt-half
        const half4 hv = *reinterpret_cast<const half4*>(&lt[0][p4][hh * 4]);
        const half4 lv = *reinterpret_cast<const half4*>(&lt[1][p4][hh * 4]);
        const int h = nt * 4 + hh;
        const size_t idx = (size_t)h * NPIX + pt * 16 + p4;
        ((half4*)((m == 0) ? qhi : khi))[idx] = hv;
        ((half4*)((m == 0) ? qlo : klo))[idx] = lv;
    }
}

// ---------------------------------------------------------------------------
// K2: fused MFMA local attention + split-K reduce + normalize, SSEG=8
// (validated R13 core).  hg==0 blocks additionally zero the 356 attpad
// border pixels at kernel start (wave 0; replaces the setup kernel's job).
// ---------------------------------------------------------------------------
__global__ __launch_bounds__(1024) void attn_mfma_kernel(
    const half4* __restrict__ qhi, const half4* __restrict__ qlo,
    const half4* __restrict__ khi, const half4* __restrict__ klo,
    const _Float16* __restrict__ vT,
    _Float16* __restrict__ attpad)
{
    __shared__ f32x4 red[16][2][64];   // 32 KB

    const int hg  = blockIdx.x / 48;
    const int qq  = blockIdx.x % 48;
    const int h   = hg >> 1, g = hg & 1;
    const int wav = __builtin_amdgcn_readfirstlane(threadIdx.x >> 6);  // 0..15
    const int seg = wav & 7;
    const int u   = wav >> 3;
    const int qt0 = qq * 4 + u * 2;           // tiles qt0, qt0+1
    const int lane = threadIdx.x & 63;
    const int c    = lane & 15;
    const int g16  = lane >> 4;
    const int c0   = g * 16;

    if (hg == 0 && wav == 0) {                // border zero (356 pad pixels)
        const int i = qq * 8 + (lane >> 3);
        if (i < 356) {
            int py, px;
            if (i < 50)       { py = 0;              px = i; }
            else if (i < 100) { py = HPAD - 1;       px = i - 50; }
            else if (i < 228) { py = 1 + (i - 100);  px = 0; }
            else              { py = 1 + (i - 228);  px = WPAD - 1; }
            const half4 z = {};
            *reinterpret_cast<half4*>(
                attpad + ((size_t)py * WPAD + px) * DM + (lane & 7) * 4) = z;
        }
    }

    half4 qfA = {}, qfB = {};
    {
        const half4* qsrc = (g16 == 1) ? qlo : qhi;
        const int qa  = qt0 * 16 + c;
        const int qay = qa / 24;
        const int qb  = qa + 16;
        const int qby = qb / 24;
        if (g16 < 3) {
            qfA = qsrc[h * NPIX + qay * W_IMG + g * 24 + (qa - qay * 24)];
            qfB = qsrc[h * NPIX + qby * W_IMG + g * 24 + (qb - qby * 24)];
        }
    }

    const half4* kb = ((g16 == 2) ? klo : khi) + h * NPIX + c;
    const int vplane = (c < 4) ? c : 4;
    const _Float16* vb = vT + (h * 5 + vplane) * NPIX + 4 * g16;

    const f32x4 zc = {0.f, 0.f, 0.f, 0.f};
    f32x4 oA0 = zc, oA1 = zc, oB0 = zc, oB1 = zc;

    const int r0 = seg * 16;
    #pragma unroll 4
    for (int r = 0; r < 16; ++r) {
        const int koff = (r0 + r) * W_IMG + c0;

        const half4 k0 = kb[koff];
        const half4 k1 = kb[koff + 16];
        const half4 v0 = *reinterpret_cast<const half4*>(vb + koff);
        const half4 v1 = *reinterpret_cast<const half4*>(vb + koff + 16);

        const f32x4 sA0 = __builtin_amdgcn_mfma_f32_16x16x16f16(k0, qfA, zc, 0, 0, 0);
        const f32x4 sA1 = __builtin_amdgcn_mfma_f32_16x16x16f16(k1, qfA, zc, 0, 0, 0);
        const f32x4 sB0 = __builtin_amdgcn_mfma_f32_16x16x16f16(k0, qfB, zc, 0, 0, 0);
        const f32x4 sB1 = __builtin_amdgcn_mfma_f32_16x16x16f16(k1, qfB, zc, 0, 0, 0);

        const half4 pA0 = exp_pack(sA0);
        const half4 pA1 = exp_pack(sA1);
        const half4 pB0 = exp_pack(sB0);
        const half4 pB1 = exp_pack(sB1);

        oA0 = __builtin_amdgcn_mfma_f32_16x16x16f16(pA0, v0, oA0, 0, 0, 0);
        oA1 = __builtin_amdgcn_mfma_f32_16x16x16f16(pA1, v1, oA1, 0, 0, 0);
        oB0 = __builtin_amdgcn_mfma_f32_16x16x16f16(pB0, v0, oB0, 0, 0, 0);
        oB1 = __builtin_amdgcn_mfma_f32_16x16x16f16(pB1, v1, oB1, 0, 0, 0);
    }

    red[wav][0][lane] = oA0 + oA1;
    red[wav][1][lane] = oB0 + oB1;
    __syncthreads();

    if (wav < 4) {
        const int u2  = wav >> 1;              // pair group
        const int t01 = wav & 1;               // tile within pair
        f32x4 o = red[u2 * 8 + 0][t01][lane];
        #pragma unroll
        for (int s = 1; s < 8; ++s)
            o += red[u2 * 8 + s][t01][lane];

        const int baddr = (g16 * 16 + 4) << 2; // ssum column lane, in bytes
        f32x4 on;
        #pragma unroll
        for (int r = 0; r < 4; ++r) {
            const float ss = __int_as_float(
                __builtin_amdgcn_ds_bpermute(baddr, __float_as_int(o[r])));
            on[r] = o[r] * __builtin_amdgcn_rcpf(ss);
        }

        if (c < 4) {
            const int qt = qq * 4 + u2 * 2 + t01;
            #pragma unroll
            for (int r = 0; r < 4; ++r) {
                const int q  = qt * 16 + 4 * g16 + r;
                const int qy = q / 24;
                const int qx = g * 24 + (q - qy * 24);
                attpad[((size_t)(qy + 1) * WPAD + qx + 1) * DM + h * 4 + c] =
                    (_Float16)on[r];
            }
        }
    }
}

// ---------------------------------------------------------------------------
// K3: output conv as MFMA GEMM, dy-split, DIRECT wo loads.
// grid = 4 nt * 384 pt blocks of 3 waves (wave = dy); LDS-sum; f32 out.
// ---------------------------------------------------------------------------
__global__ __launch_bounds__(192) void out_mfma_kernel(
    const _Float16* __restrict__ attpad,
    const float* __restrict__ wo,
    float* __restrict__ out)
{
    __shared__ f32x4 redo[2][64];

    const int pt  = blockIdx.x % 384;
    const int nt  = blockIdx.x / 384;        // 0..3
    const int wav = __builtin_amdgcn_readfirstlane(threadIdx.x >> 6);  // = dy
    const int lane = threadIdx.x & 63;
    const int r    = lane & 15;
    const int g16  = lane >> 4;

    const int y   = pt / 3;
    const int x0  = (pt % 3) * 16 + r;
    const _Float16* ab = attpad + ((size_t)y * WPAD + x0) * DM + 4 * g16;

    const int ch = nt * 16 + r;

    f32x4 a0 = {0.f, 0.f, 0.f, 0.f}, a1 = {0.f, 0.f, 0.f, 0.f};

    #pragma unroll
    for (int dx = 0; dx < 3; ++dx) {
        const int toff = (wav * WPAD + dx) * DM;
        const float* wp0 = wo + (size_t)(wav * 3 + dx) * DM * 64 + 4 * g16 * 64 + ch;
        #pragma unroll
        for (int cb = 0; cb < 2; ++cb) {
            const half4 xa = *reinterpret_cast<const half4*>(ab + toff + cb * 16);
            const float* wp = wp0 + cb * 16 * 64;
            half4 wf = { (_Float16)wp[0 * 64], (_Float16)wp[1 * 64],
                         (_Float16)wp[2 * 64], (_Float16)wp[3 * 64] };
            if (cb & 1)
                a1 = __builtin_amdgcn_mfma_f32_16x16x16f16(xa, wf, a1, 0, 0, 0);
            else
                a0 = __builtin_amdgcn_mfma_f32_16x16x16f16(xa, wf, a0, 0, 0, 0);
        }
    }

    f32x4 o = a0 + a1;
    if (wav > 0) redo[wav - 1][lane] = o;
    __syncthreads();
    if (wav != 0) return;

    o += redo[0][lane] + redo[1][lane];

    const int pix0 = pt * 16 + 4 * g16;
    #pragma unroll
    for (int j = 0; j < 4; ++j)
        out[(size_t)(pix0 + j) * 64 + nt * 16 + r] = o[j];
}

// ---------------------------------------------------------------------------
extern "C" void kernel_launch(void* const* d_in, const int* in_sizes, int n_in,
                              void* d_out, int out_size, void* d_ws, size_t ws_size,
                              hipStream_t stream)
{
    const float* x  = (const float*)d_in[0];
    const float* wq = (const float*)d_in[1];
    const float* bq = (const float*)d_in[2];
    const float* wk = (const float*)d_in[3];
    const float* bk = (const float*)d_in[4];
    const float* wv = (const float*)d_in[5];
    const float* bv = (const float*)d_in[6];
    const float* wo = (const float*)d_in[7];
    float* out = (float*)d_out;

    // workspace layout (bytes)
    char* base = (char*)d_ws;
    half4*    qhi    = (half4*)(base + 0);          //  393216
    half4*    qlo    = (half4*)(base + 393216);
    half4*    khi    = (half4*)(base + 786432);
    half4*    klo    = (half4*)(base + 1179648);
    _Float16* vT     = (_Float16*)(base + 1572864); //  491520 (8h x 5 planes)
    _Float16* attpad = (_Float16*)(base + 2064384); //  416000 -> 2480384

    hipLaunchKernelGGL(qkv_mfma_kernel, dim3(2304), dim3(192), 0, stream,
                       x, wq, bq, wk, bk, wv, bv, qhi, qlo, khi, klo, vT);

    hipLaunchKernelGGL(attn_mfma_kernel, dim3(16 * 48), dim3(1024), 0, stream,
                       qhi, qlo, khi, klo, vT, attpad);

    hipLaunchKernelGGL(out_mfma_kernel, dim3(4 * 384), dim3(192), 0, stream,
                       attpad, wo, out);
}